// Round 3
// baseline (155.711 us; speedup 1.0000x reference)
//
#include <hip/hip_runtime.h>
#include <hip/hip_bf16.h>

// Problem constants
#define P_ROWS   1024
#define N_IN     784
#define N_OUT    128
#define M_ROWS   785                 // N_IN + 1 (bias row)
#define OUT_ELEMS (P_ROWS * N_OUT)

// RATIO = G_MIN/(G_MAX-G_MIN) = 281.3/(983.3-281.3)
#define RATIO_F  ((float)((1.0/983.3) / ((1.0/281.3) - (1.0/983.3))))

// Workspace layout (bytes)
#define PART_OFF  0                  // 32 float block-max partials
#define ET_OFF    256                // e^T [785][1024] fp32 = 3,215,360 B
#define ET_BYTES  (M_ROWS * P_ROWS * 4)
#define ALT_OFF   (ET_OFF + ET_BYTES)        // 3,215,616 (16B aligned)
// AL_T [128][785] float4 {wp, log2(np), wn, log2(nn)} = 1,607,680 B

// K1 grid partition: 208 transpose blocks + 32 max blocks + 64 AL blocks
#define NB_TR   208     // 16 p-tiles x 13 m-tiles
#define NB_MAX  32
#define NB_AL   64
#define NB_K1   (NB_TR + NB_MAX + NB_AL)

// ---------------------------------------------------------------------------
// K1 (fused, no inter-block deps):
//  blocks [0,208):   e^T[m][p] = log2(2*x[p][m]) (bias row -> 1.0), LDS transpose
//  blocks [208,240): per-block max|w| partials -> partial[0..31]
//  blocks [240,304): AL_T[k][m] = {wp, log2(np), wn, log2(nn)}  (no maxw needed)
__global__ __launch_bounds__(256) void memristor_prep(
        const float* __restrict__ x,  const float* __restrict__ wp,
        const float* __restrict__ wn, const float* __restrict__ bp,
        const float* __restrict__ bn, const float* __restrict__ np,
        float* __restrict__ eT, float4* __restrict__ ALT,
        float* __restrict__ partial) {
    const int b = blockIdx.x;
    const int t = threadIdx.x;

    if (b < NB_TR) {
        // ---- transpose + log2 ----
        const int pt = b & 15, mt = b >> 4;       // 16 x 13
        const int p0 = pt * 64, m0 = mt * 64;
        const int mw = (mt == 12) ? (N_IN - 12 * 64) : 64;   // 16 or 64
        __shared__ float tile[64][65];
        const int c = t & 63, r0 = t >> 6;        // c: inner col, r0: 0..3
        for (int r = 0; r < 16; ++r) {
            int p_loc = r0 * 16 + r;
            if (c < mw)
                tile[p_loc][c] = x[(size_t)(p0 + p_loc) * N_IN + m0 + c];
        }
        __syncthreads();
        for (int r = 0; r < 16; ++r) {
            int m_loc = r0 * 16 + r;
            if (m_loc < mw) {
                float xv = tile[c][m_loc];
                float e = (xv > 0.0f) ? __builtin_amdgcn_logf(2.0f * xv) : -1.0e4f;
                eT[(size_t)(m0 + m_loc) * P_ROWS + p0 + c] = e;
            }
        }
        if (mt == 12 && t < 64)                   // bias word line: e = log2(2*1) = 1
            eT[(size_t)N_IN * P_ROWS + p0 + t] = 1.0f;
    } else if (b < NB_TR + NB_MAX) {
        // ---- max |w| partials ----
        const int nW = N_IN * N_OUT;
        int gid = (b - NB_TR) * 256 + t;
        float v = 0.0f;
        if (gid < N_OUT) v = fmaxf(fabsf(bp[gid]), fabsf(bn[gid]));
        for (int i = gid; i < nW; i += NB_MAX * 256)
            v = fmaxf(v, fmaxf(fabsf(wp[i]), fabsf(wn[i])));
        for (int off = 32; off > 0; off >>= 1)
            v = fmaxf(v, __shfl_down(v, off, 64));
        __shared__ float smax[4];
        if ((t & 63) == 0) smax[t >> 6] = v;
        __syncthreads();
        if (t == 0)
            partial[b - NB_TR] = fmaxf(fmaxf(smax[0], smax[1]), fmaxf(smax[2], smax[3]));
    } else {
        // ---- AL precompute (maxw-independent) ----
        const int nE = M_ROWS * N_OUT;            // 100480
        int gid = (b - NB_TR - NB_MAX) * 256 + t;
        for (int idx = gid; idx < nE; idx += NB_AL * 256) {
            int m = idx >> 7, k = idx & 127;
            float wpv = (m < N_IN) ? wp[m * N_OUT + k] : bp[k];
            float wnv = (m < N_IN) ? wn[m * N_OUT + k] : bn[k];
            float npv = np[m * (2 * N_OUT) + 2 * k];
            float nnv = np[m * (2 * N_OUT) + 2 * k + 1];
            float4 al;
            al.x = wpv;
            al.y = __builtin_amdgcn_logf(npv);
            al.z = wnv;
            al.w = __builtin_amdgcn_logf(nnv);
            ALT[(size_t)k * M_ROWS + m] = al;
        }
    }
}

// ---------------------------------------------------------------------------
// K2: 512 blocks (16 p-groups x 32 k-groups), 256 threads = 4 waves.
// Wave w handles k = kg*4 + w for 64 p-rows (lane = p). AL_T[k][m] is
// wave-uniform -> scalar (SGPR) loads; e^T staged in LDS per 200-row m-chunk.
// Per (m,k): 1 ds_read_b32 + 2 v_mul + 2 v_exp + 2 fma + 2 add -> trans-bound.
#define CHUNK 200
__global__ __launch_bounds__(256) void memristor_main(
        const float* __restrict__ eT, const float4* __restrict__ ALT,
        const float* __restrict__ partial, float* __restrict__ out) {
    const int b  = blockIdx.x;
    const int kg = b & 31, pg = b >> 5;
    const int p0 = pg * 64;
    const int t  = threadIdx.x;
    const int lane = t & 63;
    const int k  = kg * 4 + (t >> 6);
    const int k_u = __builtin_amdgcn_readfirstlane(k);
    const float4* __restrict__ alk = ALT + (size_t)k_u * M_ROWS;

    __shared__ float e_lds[CHUNK * 64];
    float S1 = 0.0f, S2p = 0.0f, S2n = 0.0f;

    int m0 = 0;
    for (int ch = 0; ch < 4; ++ch) {
        const int cnt = (ch == 3) ? (M_ROWS - 3 * CHUNK) : CHUNK;   // 200,200,200,185
        // stage e^T[m0..m0+cnt)[p0..p0+64) -> e_lds[mm*64 + p]
        const int c = t & 15, r = t >> 4;
        for (int mm = r; mm < cnt; mm += 16) {
            float4 v = *(const float4*)(eT + (size_t)(m0 + mm) * P_ROWS + p0 + c * 4);
            *(float4*)(e_lds + mm * 64 + c * 4) = v;
        }
        __syncthreads();
        #pragma unroll 4
        for (int mm = 0; mm < cnt; ++mm) {
            float4 al = alk[m0 + mm];             // s_load_dwordx4 (uniform)
            float e  = e_lds[mm * 64 + lane];
            float Ep = __builtin_amdgcn_exp2f(e * al.y);
            float En = __builtin_amdgcn_exp2f(e * al.w);
            S1  = fmaf(al.x, Ep, S1);
            S1  = fmaf(-al.z, En, S1);
            S2p += Ep;
            S2n += En;
        }
        __syncthreads();
        m0 += cnt;
    }

    // reduce the 32 block-max partials (cheap, once per thread)
    float v = (lane < 32) ? partial[lane] : 0.0f;
    for (int off = 16; off > 0; off >>= 1)
        v = fmaxf(v, __shfl_down(v, off, 64));
    float maxw = __shfl(v, 0, 64);

    float y = 0.5f * S1 + (0.5f * RATIO_F * maxw) * (S2p - S2n);
    out[(size_t)(p0 + lane) * N_OUT + k] = y;
}

// ---------------------------------------------------------------------------
extern "C" void kernel_launch(void* const* d_in, const int* in_sizes, int n_in,
                              void* d_out, int out_size, void* d_ws, size_t ws_size,
                              hipStream_t stream) {
    const float* x  = (const float*)d_in[0];
    const float* wp = (const float*)d_in[1];
    const float* wn = (const float*)d_in[2];
    const float* bp = (const float*)d_in[3];
    const float* bn = (const float*)d_in[4];
    const float* np = (const float*)d_in[5];
    float* out = (float*)d_out;

    float*  partial = (float*)((char*)d_ws + PART_OFF);
    float*  eT      = (float*)((char*)d_ws + ET_OFF);
    float4* ALT     = (float4*)((char*)d_ws + ALT_OFF);

    memristor_prep<<<NB_K1, 256, 0, stream>>>(x, wp, wn, bp, bn, np, eT, ALT, partial);
    memristor_main<<<512, 256, 0, stream>>>(eT, ALT, partial, out);
}

// Round 4
// 101.739 us; speedup vs baseline: 1.5305x; 1.5305x over previous
//
#include <hip/hip_runtime.h>
#include <hip/hip_bf16.h>

// Problem constants
#define P_ROWS   1024
#define N_IN     784
#define N_OUT    128
#define M_ROWS   785                 // N_IN + 1 (bias row)
#define M_PAD    816                 // 12 chunks x 68; rows 785..815 are zero-effect pads
#define OUT_ELEMS (P_ROWS * N_OUT)

// RATIO = G_MIN/(G_MAX-G_MIN) = (1/983.3)/((1/281.3)-(1/983.3))
#define RATIO_F  ((float)((1.0/983.3) / ((1.0/281.3) - (1.0/983.3))))

// main-kernel tiling
#define NCH      12
#define CHUNK    68                  // M_PAD / NCH
#define NB_MAIN  (64 * NCH)          // 64 p-blocks (16 rows) x 12 m-chunks = 768

// prep-kernel grid partition
#define NB_MAX   32
#define NB_AL    64
#define NB_PREP  (NB_MAX + NB_AL)

// Workspace layout (bytes)
#define PART_OFF 0                   // 32 float max-partials
#define AL_OFF   256                 // AL[M_PAD][128] float4 = 1,671,168 B
// ---------------------------------------------------------------------------
// K1 (fused, independent halves):
//  blocks [0,32):  per-block max|w| partials over {wp,wn,bp,bn} -> partial[b]
//  blocks [32,96): AL[m][k] = {wp, log2(np), wn, log2(nn)}  (raw w — no maxw
//                  dependency; maxw enters only in K2's epilogue via S2 term).
//                  m==784 -> bias row; m in [785,816) -> all zeros (pad:
//                  Ep=En=exp2(e*0)=1 and w=0 -> contributes 0 to S1 and S2).
__global__ __launch_bounds__(256) void memristor_prep(
        const float* __restrict__ wp, const float* __restrict__ wn,
        const float* __restrict__ bp, const float* __restrict__ bn,
        const float* __restrict__ np, float4* __restrict__ AL,
        float* __restrict__ partial) {
    const int b = blockIdx.x;
    const int t = threadIdx.x;

    if (b < NB_MAX) {
        const int nW = N_IN * N_OUT;
        int gid = b * 256 + t;
        float v = 0.0f;
        if (gid < N_OUT) v = fmaxf(fabsf(bp[gid]), fabsf(bn[gid]));
        for (int i = gid; i < nW; i += NB_MAX * 256)
            v = fmaxf(v, fmaxf(fabsf(wp[i]), fabsf(wn[i])));
        for (int off = 32; off > 0; off >>= 1)
            v = fmaxf(v, __shfl_down(v, off, 64));
        __shared__ float smax[4];
        if ((t & 63) == 0) smax[t >> 6] = v;
        __syncthreads();
        if (t == 0)
            partial[b] = fmaxf(fmaxf(smax[0], smax[1]), fmaxf(smax[2], smax[3]));
    } else {
        const int nE = M_PAD * N_OUT;            // 104448
        int gid = (b - NB_MAX) * 256 + t;
        for (int idx = gid; idx < nE; idx += NB_AL * 256) {
            int m = idx >> 7, k = idx & 127;
            float4 al;
            if (m < N_IN) {
                al.x = wp[m * N_OUT + k];
                al.z = wn[m * N_OUT + k];
                al.y = __builtin_amdgcn_logf(np[m * (2 * N_OUT) + 2 * k]);
                al.w = __builtin_amdgcn_logf(np[m * (2 * N_OUT) + 2 * k + 1]);
            } else if (m == N_IN) {
                al.x = bp[k];
                al.z = bn[k];
                al.y = __builtin_amdgcn_logf(np[N_IN * (2 * N_OUT) + 2 * k]);
                al.w = __builtin_amdgcn_logf(np[N_IN * (2 * N_OUT) + 2 * k + 1]);
            } else {
                al.x = al.y = al.z = al.w = 0.0f;   // pad row: zero contribution
            }
            AL[idx] = al;
        }
    }
}

// ---------------------------------------------------------------------------
// K2 main: 768 blocks (64 p-blocks x 12 m-chunks) = exactly 3 blocks/CU.
// Block: 16 p-rows x 68 m x all 128 k.  Waves: wid = (pg<<1)|kh; lane = k&63.
// Per (m, wave): 1x global float4 AL (coalesced, L2-hot) + 2x ds_read_b128
// (wave-uniform addr -> broadcast of 8 e-values) + 8p x {2 mul, 2 exp2,
// 2 fma, 2 add}: 96 VALU-cyc vs 128 trans-cyc -> transcendental-bound.
// y = 0.5*S1 + (0.5*RATIO*maxw)*S2, accumulated across chunks via atomics.
__global__ __launch_bounds__(256) void memristor_main(
        const float* __restrict__ x, const float4* __restrict__ AL,
        const float* __restrict__ partial, float* __restrict__ out) {
    const int bid = blockIdx.x;
    const int ch  = bid % NCH;
    const int pb  = bid / NCH;
    const int p0  = pb * 16;
    const int m0  = ch * CHUNK;
    const int t   = threadIdx.x;

    // ---- stage e = log2(2x) for this block's 16 p-rows x 68 m -> LDS[mm][p] ----
    __shared__ __align__(16) float e_lds[CHUNK * 16];   // 4352 B
    for (int idx = t; idx < 16 * CHUNK; idx += 256) {
        const int r  = idx / CHUNK;          // p-local 0..15
        const int mm = idx - r * CHUNK;      // m-local 0..67 (consecutive t -> coalesced x)
        const int m  = m0 + mm;
        float e;
        if (m < N_IN) {
            float xv = x[(size_t)(p0 + r) * N_IN + m];
            e = (xv > 0.0f) ? __builtin_amdgcn_logf(2.0f * xv) : -1.0e4f;
        } else {
            e = (m == N_IN) ? 1.0f : 0.0f;   // bias row: log2(2*1)=1; pad: dummy
        }
        e_lds[mm * 16 + r] = e;
    }
    __syncthreads();

    const int lane = t & 63;
    const int wid  = t >> 6;
    const int kh   = wid & 1;
    const int pg   = wid >> 1;               // 8-row half
    const int k    = kh * 64 + lane;

    const float4* __restrict__ alp = AL + (size_t)m0 * N_OUT + k;
    const float4* __restrict__ ebase = (const float4*)(e_lds + pg * 8);

    float S1[8], S2[8];
    #pragma unroll
    for (int i = 0; i < 8; ++i) { S1[i] = 0.0f; S2[i] = 0.0f; }

    #pragma unroll 2
    for (int mm = 0; mm < CHUNK; ++mm) {
        float4 al = alp[(size_t)mm * N_OUT];         // per-lane, coalesced 1KB/wave
        float4 e03 = ebase[mm * 4];                  // broadcast ds_read_b128
        float4 e47 = ebase[mm * 4 + 1];
        float ev[8] = {e03.x, e03.y, e03.z, e03.w, e47.x, e47.y, e47.z, e47.w};
        #pragma unroll
        for (int i = 0; i < 8; ++i) {
            float Ep = __builtin_amdgcn_exp2f(ev[i] * al.y);
            float En = __builtin_amdgcn_exp2f(ev[i] * al.w);
            S1[i] = fmaf(al.x, Ep, S1[i]);
            S1[i] = fmaf(-al.z, En, S1[i]);
            S2[i] += Ep;
            S2[i] -= En;
        }
    }

    // maxw from the 32 prep partials (reduced in-wave; cheap)
    float v = (lane < NB_MAX) ? partial[lane] : 0.0f;
    for (int off = 16; off > 0; off >>= 1)
        v = fmaxf(v, __shfl_down(v, off, 64));
    const float maxw = __shfl(v, 0, 64);
    const float c0 = 0.5f * RATIO_F * maxw;

    float* o = out + (size_t)(p0 + pg * 8) * N_OUT + k;
    #pragma unroll
    for (int i = 0; i < 8; ++i)
        unsafeAtomicAdd(o + (size_t)i * N_OUT, fmaf(0.5f, S1[i], c0 * S2[i]));
}

// ---------------------------------------------------------------------------
extern "C" void kernel_launch(void* const* d_in, const int* in_sizes, int n_in,
                              void* d_out, int out_size, void* d_ws, size_t ws_size,
                              hipStream_t stream) {
    const float* x  = (const float*)d_in[0];
    const float* wp = (const float*)d_in[1];
    const float* wn = (const float*)d_in[2];
    const float* bp = (const float*)d_in[3];
    const float* bn = (const float*)d_in[4];
    const float* np = (const float*)d_in[5];
    float* out = (float*)d_out;

    float*  partial = (float*)((char*)d_ws + PART_OFF);
    float4* AL      = (float4*)((char*)d_ws + AL_OFF);

    hipMemsetAsync(out, 0, (size_t)OUT_ELEMS * sizeof(float), stream);
    memristor_prep<<<NB_PREP, 256, 0, stream>>>(wp, wn, bp, bn, np, AL, partial);
    memristor_main<<<NB_MAIN, 256, 0, stream>>>(x, AL, partial, out);
}

// Round 5
// 93.472 us; speedup vs baseline: 1.6659x; 1.0884x over previous
//
#include <hip/hip_runtime.h>
#include <hip/hip_bf16.h>

// Problem constants
#define P_ROWS   1024
#define N_IN     784
#define N_OUT    128
#define M_ROWS   785                 // N_IN + 1 (bias row)
#define M_PAD    816                 // 12 chunks x 68; pad rows are zero-effect
#define OUT_ELEMS (P_ROWS * N_OUT)

// RATIO = G_MIN/(G_MAX-G_MIN);  L_AVG = log2(n_avg), n_avg = 2.132
#define RATIO_F  ((float)((1.0/983.3) / ((1.0/281.3) - (1.0/983.3))))
#define L_AVG_F  1.0922076f
#define LN2_F    0.6931472f

// main tiling (R4-verified skeleton)
#define NCH      12
#define CHUNK    68
#define NB_MAIN  (64 * NCH)          // 768 blocks = 3 blocks/CU

#define NB_MAX   32

// Workspace layout (bytes)
#define PART_OFF 0                   // 32 float max-partials
#define C_OFF    256                 // C[M_PAD][128] half4 = 816*128*8 B = 835,584

typedef _Float16 half4 __attribute__((ext_vector_type(4)));

// ---------------------------------------------------------------------------
// K1: per-block max|w| partials over {wp,wn,bp,bn} -> partial[0..31]
__global__ __launch_bounds__(256) void max_reduce(
        const float* __restrict__ wp, const float* __restrict__ wn,
        const float* __restrict__ bp, const float* __restrict__ bn,
        float* __restrict__ partial) {
    const int b = blockIdx.x, t = threadIdx.x;
    const int nW = N_IN * N_OUT;
    int gid = b * 256 + t;
    float v = 0.0f;
    if (gid < N_OUT) v = fmaxf(fabsf(bp[gid]), fabsf(bn[gid]));
    for (int i = gid; i < nW; i += NB_MAX * 256)
        v = fmaxf(v, fmaxf(fabsf(wp[i]), fabsf(wn[i])));
    for (int off = 32; off > 0; off >>= 1)
        v = fmaxf(v, __shfl_down(v, off, 64));
    __shared__ float smax[4];
    if ((t & 63) == 0) smax[t >> 6] = v;
    __syncthreads();
    if (t == 0)
        partial[b] = fmaxf(fmaxf(smax[0], smax[1]), fmaxf(smax[2], smax[3]));
}

// ---------------------------------------------------------------------------
// K2: Taylor-factor coefficients, f16x4 per (m,k):
//   A_p = c0 + 0.5*wp,  A_n = c0 + 0.5*wn,  D = ln(n/n_avg)
//   C_j = (A_p*Dp^j - A_n*Dn^j)/j!,  j = 0..3   (C_0 = 0.5*(wp-wn))
// Pad rows m in [785,816) -> zeros (contribute nothing).
__global__ __launch_bounds__(256) void precompute_c(
        const float* __restrict__ wp, const float* __restrict__ wn,
        const float* __restrict__ bp, const float* __restrict__ bn,
        const float* __restrict__ np, const float* __restrict__ partial,
        half4* __restrict__ C) {
    float mw = 0.0f;
    #pragma unroll
    for (int i = 0; i < NB_MAX; ++i) mw = fmaxf(mw, partial[i]);
    const float c0 = 0.5f * RATIO_F * mw;

    int idx = blockIdx.x * 256 + threadIdx.x;   // grid sized exactly M_PAD*128/256
    int m = idx >> 7, k = idx & 127;
    half4 c = {0.0f16, 0.0f16, 0.0f16, 0.0f16};
    if (m < M_ROWS) {
        float wpv = (m < N_IN) ? wp[m * N_OUT + k] : bp[k];
        float wnv = (m < N_IN) ? wn[m * N_OUT + k] : bn[k];
        float npv = np[m * (2 * N_OUT) + 2 * k];
        float nnv = np[m * (2 * N_OUT) + 2 * k + 1];
        float Dp = LN2_F * (__builtin_amdgcn_logf(npv) - L_AVG_F);  // ln(n/n_avg)
        float Dn = LN2_F * (__builtin_amdgcn_logf(nnv) - L_AVG_F);
        float Ap = c0 + 0.5f * wpv;
        float An = c0 + 0.5f * wnv;
        float ApD = Ap * Dp, AnD = An * Dn;          // A*D
        float ApD2 = ApD * Dp, AnD2 = AnD * Dn;      // A*D^2
        float ApD3 = ApD2 * Dp, AnD3 = AnD2 * Dn;    // A*D^3
        c.x = (_Float16)(Ap - An);                   // = 0.5*(wp-wn), c0 cancels
        c.y = (_Float16)(ApD - AnD);
        c.z = (_Float16)((ApD2 - AnD2) * 0.5f);
        c.w = (_Float16)((ApD3 - AnD3) * (1.0f / 6.0f));
    }
    C[idx] = c;
}

// ---------------------------------------------------------------------------
// K3 main: 768 blocks (64 p-blocks x 12 m-chunks), 3 blocks/CU, 256 threads.
// Stage F[p][mm] = {F0,F1,F2,F3} = n_avg^e * {1,e,e^2,e^3} in LDS (17.4 KB,
// e = log2(2x); 0.8M exp2 total vs 206M in the direct path). Inner loop is a
// pure fp32 4-term dot: per thread-mm 4 cvt + 32 FMA; F via wave-uniform
// broadcast ds_read_b128, C via coalesced 8B/lane global (L2-hot).
__global__ __launch_bounds__(256) void memristor_main(
        const float* __restrict__ x, const half4* __restrict__ C,
        float* __restrict__ out) {
    const int bid = blockIdx.x;
    const int ch  = bid % NCH;
    const int pb  = bid / NCH;
    const int p0  = pb * 16;
    const int m0  = ch * CHUNK;
    const int t   = threadIdx.x;

    __shared__ __align__(16) float4 F_lds[16 * CHUNK];   // [p][mm], 17.4 KB
    for (int idx = t; idx < 16 * CHUNK; idx += 256) {
        const int r  = idx / CHUNK;            // p-local
        const int mm = idx - r * CHUNK;        // m-local (tid-consecutive -> coalesced)
        const int m  = m0 + mm;
        float e;
        if (m < N_IN) {
            float xv = x[(size_t)(p0 + r) * N_IN + m];
            e = (xv > 0.0f) ? __builtin_amdgcn_logf(2.0f * xv) : -1.0e4f;
        } else {
            e = (m == N_IN) ? 1.0f : -1.0e4f;  // bias row; pad -> F=0
        }
        float F0 = __builtin_amdgcn_exp2f(e * L_AVG_F);
        float F1 = F0 * e;
        float F2 = F1 * e;
        float F3 = F2 * e;
        F_lds[r * CHUNK + mm] = make_float4(F0, F1, F2, F3);
    }
    __syncthreads();

    const int lane = t & 63;
    const int wid  = t >> 6;
    const int kh   = wid & 1;
    const int pg   = wid >> 1;                 // 8-row half
    const int k    = kh * 64 + lane;

    const half4*  __restrict__ Cp = C + (size_t)m0 * N_OUT + k;
    const float4* __restrict__ Fb = F_lds + pg * 8 * CHUNK;

    float acc[8];
    #pragma unroll
    for (int i = 0; i < 8; ++i) acc[i] = 0.0f;

    #pragma unroll 2
    for (int mm = 0; mm < CHUNK; ++mm) {
        half4 ch4 = Cp[(size_t)mm * N_OUT];    // 8B/lane coalesced, L2-hot
        float c0 = (float)ch4.x, c1 = (float)ch4.y;
        float c2 = (float)ch4.z, c3 = (float)ch4.w;
        #pragma unroll
        for (int i = 0; i < 8; ++i) {
            float4 f = Fb[i * CHUNK + mm];     // wave-uniform broadcast b128
            acc[i] = fmaf(f.x, c0,
                     fmaf(f.y, c1,
                     fmaf(f.z, c2,
                     fmaf(f.w, c3, acc[i]))));
        }
    }

    float* o = out + (size_t)(p0 + pg * 8) * N_OUT + k;
    #pragma unroll
    for (int i = 0; i < 8; ++i)
        unsafeAtomicAdd(o + (size_t)i * N_OUT, acc[i]);
}

// ---------------------------------------------------------------------------
extern "C" void kernel_launch(void* const* d_in, const int* in_sizes, int n_in,
                              void* d_out, int out_size, void* d_ws, size_t ws_size,
                              hipStream_t stream) {
    const float* x  = (const float*)d_in[0];
    const float* wp = (const float*)d_in[1];
    const float* wn = (const float*)d_in[2];
    const float* bp = (const float*)d_in[3];
    const float* bn = (const float*)d_in[4];
    const float* np = (const float*)d_in[5];
    float* out = (float*)d_out;

    float* partial = (float*)((char*)d_ws + PART_OFF);
    half4* C       = (half4*)((char*)d_ws + C_OFF);

    hipMemsetAsync(out, 0, (size_t)OUT_ELEMS * sizeof(float), stream);
    max_reduce<<<NB_MAX, 256, 0, stream>>>(wp, wn, bp, bn, partial);
    precompute_c<<<(M_PAD * N_OUT) / 256, 256, 0, stream>>>(wp, wn, bp, bn, np, partial, C);
    memristor_main<<<NB_MAIN, 256, 0, stream>>>(x, C, out);
}

// Round 6
// 89.624 us; speedup vs baseline: 1.7374x; 1.0429x over previous
//
#include <hip/hip_runtime.h>
#include <hip/hip_bf16.h>

// Problem constants
#define P_ROWS   1024
#define N_IN     784
#define N_OUT    128
#define M_ROWS   785                 // N_IN + 1 (bias row)
#define M_PAD    816                 // 24 chunks x 34; pad rows zero-effect
#define OUT_ELEMS (P_ROWS * N_OUT)

// RATIO = G_MIN/(G_MAX-G_MIN);  L_AVG = log2(n_avg), n_avg = 2.132
#define RATIO_F  ((float)((1.0/983.3) / ((1.0/281.3) - (1.0/983.3))))
#define L_AVG_F  1.0922076f
#define LN2_F    0.6931472f

// main tiling: 32 p-rows x 128 k per block, 24 m-chunks of 34
#define NCH      24
#define CHUNK    34
#define NB_MAIN  ((P_ROWS / 32) * NCH)   // 32 * 24 = 768 = 3 blocks/CU

#define NB_MAX   32

// Workspace layout (bytes)
#define PART_OFF 0                   // 32 float max-partials
#define C_OFF    256                 // C[M_PAD][128] half4 = 816*128*8 = 835,584 B

typedef _Float16 half2v __attribute__((ext_vector_type(2)));
typedef _Float16 half4v __attribute__((ext_vector_type(4)));

__device__ __forceinline__ float fdot2(half2v a, half2v b, float c) {
#if __has_builtin(__builtin_amdgcn_fdot2)
    return __builtin_amdgcn_fdot2(a, b, c, false);
#else
    return fmaf((float)a.x, (float)b.x, fmaf((float)a.y, (float)b.y, c));
#endif
}

// ---------------------------------------------------------------------------
// K1: per-block max|w| partials over {wp,wn,bp,bn} -> partial[0..31]
__global__ __launch_bounds__(256) void max_reduce(
        const float* __restrict__ wp, const float* __restrict__ wn,
        const float* __restrict__ bp, const float* __restrict__ bn,
        float* __restrict__ partial) {
    const int b = blockIdx.x, t = threadIdx.x;
    const int nW4 = (N_IN * N_OUT) / 4;       // 25088 float4s
    const float4* wp4 = (const float4*)wp;
    const float4* wn4 = (const float4*)wn;
    int gid = b * 256 + t;
    float v = 0.0f;
    if (gid < N_OUT / 4) {
        float4 a = ((const float4*)bp)[gid], c = ((const float4*)bn)[gid];
        v = fmaxf(fmaxf(fmaxf(fabsf(a.x), fabsf(a.y)), fmaxf(fabsf(a.z), fabsf(a.w))),
                  fmaxf(fmaxf(fabsf(c.x), fabsf(c.y)), fmaxf(fabsf(c.z), fabsf(c.w))));
    }
    for (int i = gid; i < nW4; i += NB_MAX * 256) {
        float4 a = wp4[i], c = wn4[i];
        v = fmaxf(v, fmaxf(fmaxf(fabsf(a.x), fabsf(a.y)), fmaxf(fabsf(a.z), fabsf(a.w))));
        v = fmaxf(v, fmaxf(fmaxf(fabsf(c.x), fabsf(c.y)), fmaxf(fabsf(c.z), fabsf(c.w))));
    }
    for (int off = 32; off > 0; off >>= 1)
        v = fmaxf(v, __shfl_down(v, off, 64));
    __shared__ float smax[4];
    if ((t & 63) == 0) smax[t >> 6] = v;
    __syncthreads();
    if (t == 0)
        partial[b] = fmaxf(fmaxf(smax[0], smax[1]), fmaxf(smax[2], smax[3]));
}

// ---------------------------------------------------------------------------
// K2: Taylor coefficients, f16x4 per (m,k):
//   A_p = c0 + 0.5*wp,  A_n = c0 + 0.5*wn,  D = ln(n/n_avg)
//   C_j = (A_p*Dp^j - A_n*Dn^j)/j!   (C_0 = 0.5*(wp-wn); c0 cancels)
// Pad rows m in [785,816) -> zeros.
__global__ __launch_bounds__(256) void precompute_c(
        const float* __restrict__ wp, const float* __restrict__ wn,
        const float* __restrict__ bp, const float* __restrict__ bn,
        const float* __restrict__ np, const float* __restrict__ partial,
        half4v* __restrict__ C) {
    float mw = 0.0f;
    #pragma unroll
    for (int i = 0; i < NB_MAX; ++i) mw = fmaxf(mw, partial[i]);
    const float c0 = 0.5f * RATIO_F * mw;

    int idx = blockIdx.x * 256 + threadIdx.x;   // grid = M_PAD*128/256
    int m = idx >> 7, k = idx & 127;
    half4v c = {0.0f16, 0.0f16, 0.0f16, 0.0f16};
    if (m < M_ROWS) {
        float wpv = (m < N_IN) ? wp[m * N_OUT + k] : bp[k];
        float wnv = (m < N_IN) ? wn[m * N_OUT + k] : bn[k];
        float npv = np[m * (2 * N_OUT) + 2 * k];
        float nnv = np[m * (2 * N_OUT) + 2 * k + 1];
        float Dp = LN2_F * (__builtin_amdgcn_logf(npv) - L_AVG_F);
        float Dn = LN2_F * (__builtin_amdgcn_logf(nnv) - L_AVG_F);
        float Ap = c0 + 0.5f * wpv;
        float An = c0 + 0.5f * wnv;
        float ApD = Ap * Dp,   AnD = An * Dn;
        float ApD2 = ApD * Dp, AnD2 = AnD * Dn;
        float ApD3 = ApD2 * Dp, AnD3 = AnD2 * Dn;
        c.x = (_Float16)(Ap - An);
        c.y = (_Float16)(ApD - AnD);
        c.z = (_Float16)((ApD2 - AnD2) * 0.5f);
        c.w = (_Float16)((ApD3 - AnD3) * (1.0f / 6.0f));
    }
    C[idx] = c;
}

// ---------------------------------------------------------------------------
// K3 main: 768 blocks (32 p-blocks of 32 rows x 24 m-chunks of 34), 3/CU.
// F[p][mm] = n_avg^e * {1,e,e^2,e^3} staged as f16x4 in LDS (8.7 KB,
// conflict-free writes: consecutive tid -> consecutive mm, 8B stride).
// Waves: pg = tid>>6 owns 8 p-rows; lane = k, k_tile = {k, k+64}.
// Per wave-mm: 8 broadcast ds_read_b64 (48 cyc) + 2 coalesced 8B C-loads +
// 32 v_dot2_f32_f16 (~70 cyc VALU) -> VALU-bound, LDS at ~65%.
__global__ __launch_bounds__(256) void memristor_main(
        const float* __restrict__ x, const half4v* __restrict__ C,
        float* __restrict__ out) {
    const int bid = blockIdx.x;
    const int ch  = bid % NCH;
    const int pb  = bid / NCH;
    const int p0  = pb * 32;
    const int m0  = ch * CHUNK;
    const int t   = threadIdx.x;

    __shared__ half4v F_lds[32][CHUNK];        // [p_local][mm], 8704 B
    for (int idx = t; idx < 32 * CHUNK; idx += 256) {
        const int r  = idx / CHUNK;
        const int mm = idx - r * CHUNK;
        const int m  = m0 + mm;
        float e;
        if (m < N_IN) {
            float xv = x[(size_t)(p0 + r) * N_IN + m];
            e = (xv > 0.0f) ? __builtin_amdgcn_logf(2.0f * xv) : -1.0e4f;
        } else {
            e = (m == N_IN) ? 1.0f : -1.0e4f;  // bias row; pad -> F = 0
        }
        float F0 = __builtin_amdgcn_exp2f(e * L_AVG_F);
        float F1 = F0 * e;
        float F2 = F1 * e;
        float F3 = F2 * e;
        half4v f = {(_Float16)F0, (_Float16)F1, (_Float16)F2, (_Float16)F3};
        F_lds[r][mm] = f;
    }
    __syncthreads();

    const int lane = t & 63;
    const int pg   = t >> 6;                   // 8-row group
    const int k    = lane;

    const half4v* __restrict__ Cp = C + (size_t)m0 * N_OUT + k;
    const half4v* __restrict__ Fb = &F_lds[pg * 8][0];

    float acc[16];
    #pragma unroll
    for (int i = 0; i < 16; ++i) acc[i] = 0.0f;

    for (int mm = 0; mm < CHUNK; ++mm) {
        half4v c0 = Cp[(size_t)mm * N_OUT];        // k       (8B/lane coalesced)
        half4v c1 = Cp[(size_t)mm * N_OUT + 64];   // k + 64
        half2v c0a = {c0.x, c0.y}, c0b = {c0.z, c0.w};
        half2v c1a = {c1.x, c1.y}, c1b = {c1.z, c1.w};
        #pragma unroll
        for (int i = 0; i < 8; ++i) {
            half4v f = Fb[i * CHUNK + mm];         // broadcast ds_read_b64
            half2v fa = {f.x, f.y}, fb = {f.z, f.w};
            acc[2 * i]     = fdot2(fa, c0a, fdot2(fb, c0b, acc[2 * i]));
            acc[2 * i + 1] = fdot2(fa, c1a, fdot2(fb, c1b, acc[2 * i + 1]));
        }
    }

    float* o = out + (size_t)(p0 + pg * 8) * N_OUT + k;
    #pragma unroll
    for (int i = 0; i < 8; ++i) {
        unsafeAtomicAdd(o + (size_t)i * N_OUT,      acc[2 * i]);
        unsafeAtomicAdd(o + (size_t)i * N_OUT + 64, acc[2 * i + 1]);
    }
}

// ---------------------------------------------------------------------------
extern "C" void kernel_launch(void* const* d_in, const int* in_sizes, int n_in,
                              void* d_out, int out_size, void* d_ws, size_t ws_size,
                              hipStream_t stream) {
    const float* x  = (const float*)d_in[0];
    const float* wp = (const float*)d_in[1];
    const float* wn = (const float*)d_in[2];
    const float* bp = (const float*)d_in[3];
    const float* bn = (const float*)d_in[4];
    const float* np = (const float*)d_in[5];
    float* out = (float*)d_out;

    float*  partial = (float*)((char*)d_ws + PART_OFF);
    half4v* C       = (half4v*)((char*)d_ws + C_OFF);

    hipMemsetAsync(out, 0, (size_t)OUT_ELEMS * sizeof(float), stream);
    max_reduce<<<NB_MAX, 256, 0, stream>>>(wp, wn, bp, bn, partial);
    precompute_c<<<(M_PAD * N_OUT) / 256, 256, 0, stream>>>(wp, wn, bp, bn, np, partial, C);
    memristor_main<<<NB_MAIN, 256, 0, stream>>>(x, C, out);
}

// Round 7
// 78.583 us; speedup vs baseline: 1.9815x; 1.1405x over previous
//
#include <hip/hip_runtime.h>
#include <hip/hip_bf16.h>

// Problem constants
#define P_ROWS   1024
#define N_IN     784
#define N_OUT    128
#define M_ROWS   785                 // N_IN + 1 (bias row)
#define OUT_ELEMS (P_ROWS * N_OUT)

// RATIO = G_MIN/(G_MAX-G_MIN);  L_AVG = log2(n_avg), n_avg = 2.132
#define RATIO_F  ((float)((1.0/983.3) / ((1.0/281.3) - (1.0/983.3))))
#define L_AVG_F  1.0922076f
#define LN2_F    0.6931472f

// GEMM shape: K = m-rows * 4 Taylor terms. 12 chunks of 72 m-rows (288 K).
#define NCHK   12
#define MCH    72
#define KCH    (MCH * 4)             // 288
#define NSTEP  (KCH / 32)            // 9 mfma steps of K=32
#define M_TOT  (NCHK * MCH)          // 864 (rows >= 785 are zero-coeff pads)
#define NB_MAIN (64 * NCHK)          // 64 p-blocks x 12 chunks = 768 = 3/CU

#define NB_MAX 32

// Workspace layout (bytes)
#define PART_MAX_OFF 0                       // 32 float max-partials
#define CR_OFF       256                     // C_reord: M_TOT*4*128 f16 = 884,736 B
#define CR_BYTES     ((size_t)M_TOT * 4 * 128 * 2)
#define PARTIAL_OFF  (CR_OFF + CR_BYTES)     // part[12][1024][128] f32 = 6 MB

typedef _Float16 half8 __attribute__((ext_vector_type(8)));
typedef float    f32x4 __attribute__((ext_vector_type(4)));

// ---------------------------------------------------------------------------
// K1: per-block max|w| partials over {wp,wn,bp,bn} -> partial[0..31]
__global__ __launch_bounds__(256) void max_reduce(
        const float* __restrict__ wp, const float* __restrict__ wn,
        const float* __restrict__ bp, const float* __restrict__ bn,
        float* __restrict__ partial) {
    const int b = blockIdx.x, t = threadIdx.x;
    const int nW4 = (N_IN * N_OUT) / 4;
    const float4* wp4 = (const float4*)wp;
    const float4* wn4 = (const float4*)wn;
    int gid = b * 256 + t;
    float v = 0.0f;
    if (gid < N_OUT / 4) {
        float4 a = ((const float4*)bp)[gid], c = ((const float4*)bn)[gid];
        v = fmaxf(fmaxf(fmaxf(fabsf(a.x), fabsf(a.y)), fmaxf(fabsf(a.z), fabsf(a.w))),
                  fmaxf(fmaxf(fabsf(c.x), fabsf(c.y)), fmaxf(fabsf(c.z), fabsf(c.w))));
    }
    for (int i = gid; i < nW4; i += NB_MAX * 256) {
        float4 a = wp4[i], c = wn4[i];
        v = fmaxf(v, fmaxf(fmaxf(fabsf(a.x), fabsf(a.y)), fmaxf(fabsf(a.z), fabsf(a.w))));
        v = fmaxf(v, fmaxf(fmaxf(fabsf(c.x), fabsf(c.y)), fmaxf(fabsf(c.z), fabsf(c.w))));
    }
    for (int off = 32; off > 0; off >>= 1)
        v = fmaxf(v, __shfl_down(v, off, 64));
    __shared__ float smax[4];
    if ((t & 63) == 0) smax[t >> 6] = v;
    __syncthreads();
    if (t == 0)
        partial[b] = fmaxf(fmaxf(smax[0], smax[1]), fmaxf(smax[2], smax[3]));
}

// ---------------------------------------------------------------------------
// K2: Taylor coeffs C_j (j=0..3) per (m,n), written in B-FRAGMENT order:
//   Cr[c][s][q][n][j8]  where k_local = ml*4 + jj,  s = ml>>3, q = (ml>>1)&3,
//   j8 = (ml&1)*4 + jj.  One 8B (f16x4) write per (m,n).
//   C_0 = 0.5(wp-wn); C_j = (Ap*Dp^j - An*Dn^j)/j!, A = c0 + 0.5w, D = ln(n/n_avg).
__global__ __launch_bounds__(256) void precompute_c(
        const float* __restrict__ wp, const float* __restrict__ wn,
        const float* __restrict__ bp, const float* __restrict__ bn,
        const float* __restrict__ np, const float* __restrict__ partial,
        _Float16* __restrict__ Cr) {
    float mw = 0.0f;
    #pragma unroll
    for (int i = 0; i < NB_MAX; ++i) mw = fmaxf(mw, partial[i]);
    const float c0 = 0.5f * RATIO_F * mw;

    int idx = blockIdx.x * 256 + threadIdx.x;     // grid = M_TOT*128/256 = 432
    int m = idx >> 7, n = idx & 127;
    float C0 = 0.f, C1 = 0.f, C2 = 0.f, C3 = 0.f;
    if (m < M_ROWS) {
        float wpv = (m < N_IN) ? wp[m * N_OUT + n] : bp[n];
        float wnv = (m < N_IN) ? wn[m * N_OUT + n] : bn[n];
        float npv = np[m * (2 * N_OUT) + 2 * n];
        float nnv = np[m * (2 * N_OUT) + 2 * n + 1];
        float Dp = LN2_F * (__builtin_amdgcn_logf(npv) - L_AVG_F);
        float Dn = LN2_F * (__builtin_amdgcn_logf(nnv) - L_AVG_F);
        float Ap = c0 + 0.5f * wpv;
        float An = c0 + 0.5f * wnv;
        float ApD = Ap * Dp,    AnD = An * Dn;
        float ApD2 = ApD * Dp,  AnD2 = AnD * Dn;
        float ApD3 = ApD2 * Dp, AnD3 = AnD2 * Dn;
        C0 = Ap - An;                              // c0 cancels
        C1 = ApD - AnD;
        C2 = (ApD2 - AnD2) * 0.5f;
        C3 = (ApD3 - AnD3) * (1.0f / 6.0f);
    }
    const int c  = m / MCH;
    const int ml = m - c * MCH;
    const int s  = ml >> 3;
    const int q  = (ml >> 1) & 3;
    const int h  = (ml & 1) * 4;
    _Float16* dst = Cr + (((((size_t)c * NSTEP + s) * 4 + q) * 128 + n) * 8 + h);
    dst[0] = (_Float16)C0;
    dst[1] = (_Float16)C1;
    dst[2] = (_Float16)C2;
    dst[3] = (_Float16)C3;
}

// ---------------------------------------------------------------------------
// K3 main: MFMA micro-GEMM. 768 blocks (64 p-blocks x 12 chunks), 256 thr.
// F (A-operand) built in LDS in fragment order [sq][p] half8:
//   A[m=lane&15][k=quad*8+j], k = s*32+quad*8+j -> (m_row = k>>2, jj = k&3),
//   F_jj = n_avg^e * e^jj, e = log2(2x).  B streamed from Cr (coalesced 16B).
// No barrier in K-loop, no atomics: partials stored, combined by K4.
__global__ __launch_bounds__(256) void memristor_main(
        const float* __restrict__ x, const _Float16* __restrict__ Cr,
        float* __restrict__ part) {
    const int bid = blockIdx.x;
    const int ch  = bid % NCHK;
    const int pb  = bid / NCHK;
    const int p0  = pb * 16;
    const int m0  = ch * MCH;
    const int t   = threadIdx.x;

    __shared__ half8 F_lds[36 * 16];               // [sq][p], 9216 B
    for (int pm = t; pm < 16 * MCH; pm += 256) {
        const int p  = pm / MCH;
        const int ml = pm - p * MCH;
        const int m  = m0 + ml;
        float e;
        if (m < N_IN) {
            float xv = x[(size_t)(p0 + p) * N_IN + m];
            e = (xv > 0.0f) ? __builtin_amdgcn_logf(2.0f * xv) : -1.0e4f;
        } else {
            e = (m == N_IN) ? 1.0f : -1.0e4f;      // bias row; pads -> F = 0
        }
        float F0 = __builtin_amdgcn_exp2f(e * L_AVG_F);   // exp2(-1e4)=0 -> all F=+-0
        float F1 = F0 * e, F2 = F1 * e, F3 = F2 * e;
        _Float16* dst = (_Float16*)&F_lds[(ml >> 1) * 16 + p] + (ml & 1) * 4;
        dst[0] = (_Float16)F0;
        dst[1] = (_Float16)F1;
        dst[2] = (_Float16)F2;
        dst[3] = (_Float16)F3;
    }
    __syncthreads();

    const int lane = t & 63;
    const int w    = t >> 6;
    const int quad = lane >> 4;
    const int col  = lane & 15;
    const int n0   = w * 32;                       // wave covers n0..n0+31 (2 tiles)

    const _Float16* __restrict__ Bb = Cr + (size_t)ch * (NSTEP * 4 * 128 * 8);

    f32x4 acc0 = {0.f, 0.f, 0.f, 0.f};
    f32x4 acc1 = {0.f, 0.f, 0.f, 0.f};
    #pragma unroll 3
    for (int s = 0; s < NSTEP; ++s) {
        half8 a  = F_lds[(s * 4 + quad) * 16 + col];                       // ds_read_b128
        half8 b0 = *(const half8*)(Bb + (((s * 4 + quad) * 128) + n0 + col) * 8);
        half8 b1 = *(const half8*)(Bb + (((s * 4 + quad) * 128) + n0 + 16 + col) * 8);
        acc0 = __builtin_amdgcn_mfma_f32_16x16x32_f16(a, b0, acc0, 0, 0, 0);
        acc1 = __builtin_amdgcn_mfma_f32_16x16x32_f16(a, b1, acc1, 0, 0, 0);
    }

    // D layout: row = quad*4 + r, col = lane&15
    float* pbase = part + (size_t)ch * OUT_ELEMS + (size_t)(p0 + quad * 4) * N_OUT;
    #pragma unroll
    for (int r = 0; r < 4; ++r) {
        pbase[(size_t)r * N_OUT + n0 + col]      = acc0[r];
        pbase[(size_t)r * N_OUT + n0 + 16 + col] = acc1[r];
    }
}

// ---------------------------------------------------------------------------
// K4: out = sum of 12 chunk partials (float4 lanes, 128 blocks)
__global__ __launch_bounds__(256) void combine(
        const float* __restrict__ part, float* __restrict__ out) {
    const int i = blockIdx.x * 256 + threadIdx.x;          // float4 index
    const float4* p4 = (const float4*)part;
    float4 s = p4[i];
    #pragma unroll
    for (int c = 1; c < NCHK; ++c) {
        float4 v = p4[(size_t)c * (OUT_ELEMS / 4) + i];
        s.x += v.x; s.y += v.y; s.z += v.z; s.w += v.w;
    }
    ((float4*)out)[i] = s;
}

// ---------------------------------------------------------------------------
extern "C" void kernel_launch(void* const* d_in, const int* in_sizes, int n_in,
                              void* d_out, int out_size, void* d_ws, size_t ws_size,
                              hipStream_t stream) {
    const float* x  = (const float*)d_in[0];
    const float* wp = (const float*)d_in[1];
    const float* wn = (const float*)d_in[2];
    const float* bp = (const float*)d_in[3];
    const float* bn = (const float*)d_in[4];
    const float* np = (const float*)d_in[5];
    float* out = (float*)d_out;

    float*     partial = (float*)((char*)d_ws + PART_MAX_OFF);
    _Float16*  Cr      = (_Float16*)((char*)d_ws + CR_OFF);
    float*     part    = (float*)((char*)d_ws + PARTIAL_OFF);

    max_reduce<<<NB_MAX, 256, 0, stream>>>(wp, wn, bp, bn, partial);
    precompute_c<<<(M_TOT * 128) / 256, 256, 0, stream>>>(wp, wn, bp, bn, np, partial, Cr);
    memristor_main<<<NB_MAIN, 256, 0, stream>>>(x, Cr, part);
    combine<<<OUT_ELEMS / 4 / 256, 256, 0, stream>>>(part, out);
}

// Round 8
// 78.202 us; speedup vs baseline: 1.9911x; 1.0049x over previous
//
#include <hip/hip_runtime.h>
#include <hip/hip_bf16.h>

// Problem constants
#define P_ROWS   1024
#define N_IN     784
#define N_OUT    128
#define M_ROWS   785                 // N_IN + 1 (bias row)
#define OUT_ELEMS (P_ROWS * N_OUT)

// RATIO = G_MIN/(G_MAX-G_MIN);  L_AVG = log2(n_avg), n_avg = 2.132
#define RATIO_F  ((float)((1.0/983.3) / ((1.0/281.3) - (1.0/983.3))))
#define L_AVG_F  1.0922076f
#define LN2_F    0.6931472f

// GEMM shape: K = m-rows * 4 Taylor terms. 12 chunks of 72 m-rows (288 K).
#define NCHK   12
#define MCH    72
#define KCH    (MCH * 4)             // 288
#define NSTEP  (KCH / 32)            // 9 mfma steps of K=32
#define M_TOT  (NCHK * MCH)          // 864 (rows >= 785 are zero-coeff pads)
#define NB_MAIN (64 * NCHK)          // 64 p-blocks x 12 chunks = 768 = 3/CU

#define NB_MAX 32

// Workspace layout (bytes)
#define PART_MAX_OFF 0                       // 32 float max-partials
#define CR_OFF       256                     // C_reord: M_TOT*4*128 f16 = 884,736 B

typedef _Float16 half8 __attribute__((ext_vector_type(8)));
typedef float    f32x4 __attribute__((ext_vector_type(4)));

// ---------------------------------------------------------------------------
// K1: per-block max|w| partials over {wp,wn,bp,bn} -> partial[0..31]
__global__ __launch_bounds__(256) void max_reduce(
        const float* __restrict__ wp, const float* __restrict__ wn,
        const float* __restrict__ bp, const float* __restrict__ bn,
        float* __restrict__ partial) {
    const int b = blockIdx.x, t = threadIdx.x;
    const int nW4 = (N_IN * N_OUT) / 4;
    const float4* wp4 = (const float4*)wp;
    const float4* wn4 = (const float4*)wn;
    int gid = b * 256 + t;
    float v = 0.0f;
    if (gid < N_OUT / 4) {
        float4 a = ((const float4*)bp)[gid], c = ((const float4*)bn)[gid];
        v = fmaxf(fmaxf(fmaxf(fabsf(a.x), fabsf(a.y)), fmaxf(fabsf(a.z), fabsf(a.w))),
                  fmaxf(fmaxf(fabsf(c.x), fabsf(c.y)), fmaxf(fabsf(c.z), fabsf(c.w))));
    }
    for (int i = gid; i < nW4; i += NB_MAX * 256) {
        float4 a = wp4[i], c = wn4[i];
        v = fmaxf(v, fmaxf(fmaxf(fabsf(a.x), fabsf(a.y)), fmaxf(fabsf(a.z), fabsf(a.w))));
        v = fmaxf(v, fmaxf(fmaxf(fabsf(c.x), fabsf(c.y)), fmaxf(fabsf(c.z), fabsf(c.w))));
    }
    for (int off = 32; off > 0; off >>= 1)
        v = fmaxf(v, __shfl_down(v, off, 64));
    __shared__ float smax[4];
    if ((t & 63) == 0) smax[t >> 6] = v;
    __syncthreads();
    if (t == 0)
        partial[b] = fmaxf(fmaxf(smax[0], smax[1]), fmaxf(smax[2], smax[3]));
}

// ---------------------------------------------------------------------------
// K2: Taylor coeffs C_j (j=0..3) per (m,n), written in B-FRAGMENT order:
//   Cr[c][s][q][n][j8]  where k_local = ml*4 + jj,  s = ml>>3, q = (ml>>1)&3,
//   j8 = (ml&1)*4 + jj.  One 8B (f16x4) write per (m,n).
//   C_0 = 0.5(wp-wn); C_j = (Ap*Dp^j - An*Dn^j)/j!, A = c0 + 0.5w, D = ln(n/n_avg).
__global__ __launch_bounds__(256) void precompute_c(
        const float* __restrict__ wp, const float* __restrict__ wn,
        const float* __restrict__ bp, const float* __restrict__ bn,
        const float* __restrict__ np, const float* __restrict__ partial,
        _Float16* __restrict__ Cr) {
    float mw = 0.0f;
    #pragma unroll
    for (int i = 0; i < NB_MAX; ++i) mw = fmaxf(mw, partial[i]);
    const float c0 = 0.5f * RATIO_F * mw;

    int idx = blockIdx.x * 256 + threadIdx.x;     // grid = M_TOT*128/256 = 432
    int m = idx >> 7, n = idx & 127;
    float C0 = 0.f, C1 = 0.f, C2 = 0.f, C3 = 0.f;
    if (m < M_ROWS) {
        float wpv = (m < N_IN) ? wp[m * N_OUT + n] : bp[n];
        float wnv = (m < N_IN) ? wn[m * N_OUT + n] : bn[n];
        float npv = np[m * (2 * N_OUT) + 2 * n];
        float nnv = np[m * (2 * N_OUT) + 2 * n + 1];
        float Dp = LN2_F * (__builtin_amdgcn_logf(npv) - L_AVG_F);
        float Dn = LN2_F * (__builtin_amdgcn_logf(nnv) - L_AVG_F);
        float Ap = c0 + 0.5f * wpv;
        float An = c0 + 0.5f * wnv;
        float ApD = Ap * Dp,    AnD = An * Dn;
        float ApD2 = ApD * Dp,  AnD2 = AnD * Dn;
        float ApD3 = ApD2 * Dp, AnD3 = AnD2 * Dn;
        C0 = Ap - An;                              // c0 cancels
        C1 = ApD - AnD;
        C2 = (ApD2 - AnD2) * 0.5f;
        C3 = (ApD3 - AnD3) * (1.0f / 6.0f);
    }
    const int c  = m / MCH;
    const int ml = m - c * MCH;
    const int s  = ml >> 3;
    const int q  = (ml >> 1) & 3;
    const int h  = (ml & 1) * 4;
    _Float16* dst = Cr + (((((size_t)c * NSTEP + s) * 4 + q) * 128 + n) * 8 + h);
    dst[0] = (_Float16)C0;
    dst[1] = (_Float16)C1;
    dst[2] = (_Float16)C2;
    dst[3] = (_Float16)C3;
}

// ---------------------------------------------------------------------------
// K3 main: MFMA micro-GEMM. 768 blocks (64 p-blocks x 12 chunks), 256 thr.
// F (A-operand) built in LDS in fragment order [sq][p] half8:
//   A[m=lane&15][k=quad*8+j], k = s*32+quad*8+j -> (m_row = k>>2, jj = k&3),
//   F_jj = n_avg^e * e^jj, e = log2(2x).  B streamed from Cr (coalesced 16B).
// Epilogue: unsafeAtomicAdd into out (pre-zeroed; 12 adds/output — verified
// bit-stable in R4-R6). No part array, no combine pass.
__global__ __launch_bounds__(256) void memristor_main(
        const float* __restrict__ x, const _Float16* __restrict__ Cr,
        float* __restrict__ out) {
    const int bid = blockIdx.x;
    const int ch  = bid % NCHK;
    const int pb  = bid / NCHK;
    const int p0  = pb * 16;
    const int m0  = ch * MCH;
    const int t   = threadIdx.x;

    __shared__ half8 F_lds[36 * 16];               // [sq][p], 9216 B
    for (int pm = t; pm < 16 * MCH; pm += 256) {
        const int p  = pm / MCH;
        const int ml = pm - p * MCH;
        const int m  = m0 + ml;
        float e;
        if (m < N_IN) {
            float xv = x[(size_t)(p0 + p) * N_IN + m];
            e = (xv > 0.0f) ? __builtin_amdgcn_logf(2.0f * xv) : -1.0e4f;
        } else {
            e = (m == N_IN) ? 1.0f : -1.0e4f;      // bias row; pads -> F = 0
        }
        float F0 = __builtin_amdgcn_exp2f(e * L_AVG_F);   // exp2(-1e4)=0 -> all F=0
        float F1 = F0 * e, F2 = F1 * e, F3 = F2 * e;
        _Float16* dst = (_Float16*)&F_lds[(ml >> 1) * 16 + p] + (ml & 1) * 4;
        dst[0] = (_Float16)F0;
        dst[1] = (_Float16)F1;
        dst[2] = (_Float16)F2;
        dst[3] = (_Float16)F3;
    }
    __syncthreads();

    const int lane = t & 63;
    const int w    = t >> 6;
    const int quad = lane >> 4;
    const int col  = lane & 15;
    const int n0   = w * 32;                       // wave covers n0..n0+31 (2 tiles)

    const _Float16* __restrict__ Bb = Cr + (size_t)ch * (NSTEP * 4 * 128 * 8);

    f32x4 acc0 = {0.f, 0.f, 0.f, 0.f};
    f32x4 acc1 = {0.f, 0.f, 0.f, 0.f};
    #pragma unroll
    for (int s = 0; s < NSTEP; ++s) {
        half8 a  = F_lds[(s * 4 + quad) * 16 + col];                       // ds_read_b128
        half8 b0 = *(const half8*)(Bb + (((s * 4 + quad) * 128) + n0 + col) * 8);
        half8 b1 = *(const half8*)(Bb + (((s * 4 + quad) * 128) + n0 + 16 + col) * 8);
        acc0 = __builtin_amdgcn_mfma_f32_16x16x32_f16(a, b0, acc0, 0, 0, 0);
        acc1 = __builtin_amdgcn_mfma_f32_16x16x32_f16(a, b1, acc1, 0, 0, 0);
    }

    // D layout: row = quad*4 + r, col = lane&15. 8 coalesced f32 atomics/lane.
    float* obase = out + (size_t)(p0 + quad * 4) * N_OUT;
    #pragma unroll
    for (int r = 0; r < 4; ++r) {
        unsafeAtomicAdd(&obase[(size_t)r * N_OUT + n0 + col],      acc0[r]);
        unsafeAtomicAdd(&obase[(size_t)r * N_OUT + n0 + 16 + col], acc1[r]);
    }
}

// ---------------------------------------------------------------------------
extern "C" void kernel_launch(void* const* d_in, const int* in_sizes, int n_in,
                              void* d_out, int out_size, void* d_ws, size_t ws_size,
                              hipStream_t stream) {
    const float* x  = (const float*)d_in[0];
    const float* wp = (const float*)d_in[1];
    const float* wn = (const float*)d_in[2];
    const float* bp = (const float*)d_in[3];
    const float* bn = (const float*)d_in[4];
    const float* np = (const float*)d_in[5];
    float* out = (float*)d_out;

    float*     partial = (float*)((char*)d_ws + PART_MAX_OFF);
    _Float16*  Cr      = (_Float16*)((char*)d_ws + CR_OFF);

    hipMemsetAsync(out, 0, (size_t)OUT_ELEMS * sizeof(float), stream);
    max_reduce<<<NB_MAX, 256, 0, stream>>>(wp, wn, bp, bn, partial);
    precompute_c<<<(M_TOT * 128) / 256, 256, 0, stream>>>(wp, wn, bp, bn, np, partial, Cr);
    memristor_main<<<NB_MAIN, 256, 0, stream>>>(x, Cr, out);
}

// Round 9
// 75.783 us; speedup vs baseline: 2.0547x; 1.0319x over previous
//
#include <hip/hip_runtime.h>
#include <hip/hip_bf16.h>

// Problem constants
#define P_ROWS   1024
#define N_IN     784
#define N_OUT    128
#define M_ROWS   785                 // N_IN + 1 (bias row)
#define OUT_ELEMS (P_ROWS * N_OUT)

// RATIO = G_MIN/(G_MAX-G_MIN);  L_AVG = log2(n_avg), n_avg = 2.132
#define RATIO_F  ((float)((1.0/983.3) / ((1.0/281.3) - (1.0/983.3))))
#define L_AVG_F  1.0922076f
#define LN2_F    0.6931472f

// GEMM shape: K = m-rows * 4 Taylor terms. 12 chunks of 72 m-rows (288 K).
#define NCHK   12
#define MCH    72
#define KCH    (MCH * 4)             // 288
#define NSTEP  (KCH / 32)            // 9 mfma steps of K=32
#define M_TOT  (NCHK * MCH)          // 864 (rows >= 785 are zero-coeff pads)
#define NB_MAIN (64 * NCHK)          // 64 p-blocks x 12 chunks = 768 = 3/CU

#define NB_MAX 32

// Workspace layout (bytes)
#define PART_MAX_OFF 0                       // 32 float max-partials
#define CR_OFF       256                     // C_reord: M_TOT*4*128 f16 = 884,736 B

typedef _Float16 half8 __attribute__((ext_vector_type(8)));
typedef float    f32x4 __attribute__((ext_vector_type(4)));

// ---------------------------------------------------------------------------
// K1: per-block max|w| partials over {wp,wn,bp,bn} -> partial[0..31],
//     PLUS zero out[] (each block zeroes a 16 KB slice) — replaces the
//     hipMemsetAsync node; out is fully rewritten here before K3 accumulates.
__global__ __launch_bounds__(256) void max_reduce_zero(
        const float* __restrict__ wp, const float* __restrict__ wn,
        const float* __restrict__ bp, const float* __restrict__ bn,
        float* __restrict__ partial, float4* __restrict__ out4) {
    const int b = blockIdx.x, t = threadIdx.x;

    // zero this block's slice of out: 32 blocks x 1024 float4 = 131072 floats
    const float4 z = make_float4(0.f, 0.f, 0.f, 0.f);
    #pragma unroll
    for (int i = 0; i < 4; ++i)
        out4[(size_t)b * 1024 + i * 256 + t] = z;

    const int nW4 = (N_IN * N_OUT) / 4;
    const float4* wp4 = (const float4*)wp;
    const float4* wn4 = (const float4*)wn;
    int gid = b * 256 + t;
    float v = 0.0f;
    if (gid < N_OUT / 4) {
        float4 a = ((const float4*)bp)[gid], c = ((const float4*)bn)[gid];
        v = fmaxf(fmaxf(fmaxf(fabsf(a.x), fabsf(a.y)), fmaxf(fabsf(a.z), fabsf(a.w))),
                  fmaxf(fmaxf(fabsf(c.x), fabsf(c.y)), fmaxf(fabsf(c.z), fabsf(c.w))));
    }
    for (int i = gid; i < nW4; i += NB_MAX * 256) {
        float4 a = wp4[i], c = wn4[i];
        v = fmaxf(v, fmaxf(fmaxf(fabsf(a.x), fabsf(a.y)), fmaxf(fabsf(a.z), fabsf(a.w))));
        v = fmaxf(v, fmaxf(fmaxf(fabsf(c.x), fabsf(c.y)), fmaxf(fabsf(c.z), fabsf(c.w))));
    }
    for (int off = 32; off > 0; off >>= 1)
        v = fmaxf(v, __shfl_down(v, off, 64));
    __shared__ float smax[4];
    if ((t & 63) == 0) smax[t >> 6] = v;
    __syncthreads();
    if (t == 0)
        partial[b] = fmaxf(fmaxf(smax[0], smax[1]), fmaxf(smax[2], smax[3]));
}

// ---------------------------------------------------------------------------
// K2: Taylor coeffs C_j (j=0..3) per (m,n), written in B-FRAGMENT order:
//   Cr[c][s][q][n][j8]  where k_local = ml*4 + jj,  s = ml>>3, q = (ml>>1)&3,
//   j8 = (ml&1)*4 + jj.  One 8B (f16x4) write per (m,n).
//   C_0 = 0.5(wp-wn); C_j = (Ap*Dp^j - An*Dn^j)/j!, A = c0 + 0.5w, D = ln(n/n_avg).
__global__ __launch_bounds__(256) void precompute_c(
        const float* __restrict__ wp, const float* __restrict__ wn,
        const float* __restrict__ bp, const float* __restrict__ bn,
        const float* __restrict__ np, const float* __restrict__ partial,
        _Float16* __restrict__ Cr) {
    float mw = 0.0f;
    #pragma unroll
    for (int i = 0; i < NB_MAX; ++i) mw = fmaxf(mw, partial[i]);
    const float c0 = 0.5f * RATIO_F * mw;

    int idx = blockIdx.x * 256 + threadIdx.x;     // grid = M_TOT*128/256 = 432
    int m = idx >> 7, n = idx & 127;
    float C0 = 0.f, C1 = 0.f, C2 = 0.f, C3 = 0.f;
    if (m < M_ROWS) {
        float wpv = (m < N_IN) ? wp[m * N_OUT + n] : bp[n];
        float wnv = (m < N_IN) ? wn[m * N_OUT + n] : bn[n];
        float npv = np[m * (2 * N_OUT) + 2 * n];
        float nnv = np[m * (2 * N_OUT) + 2 * n + 1];
        float Dp = LN2_F * (__builtin_amdgcn_logf(npv) - L_AVG_F);
        float Dn = LN2_F * (__builtin_amdgcn_logf(nnv) - L_AVG_F);
        float Ap = c0 + 0.5f * wpv;
        float An = c0 + 0.5f * wnv;
        float ApD = Ap * Dp,    AnD = An * Dn;
        float ApD2 = ApD * Dp,  AnD2 = AnD * Dn;
        float ApD3 = ApD2 * Dp, AnD3 = AnD2 * Dn;
        C0 = Ap - An;                              // c0 cancels
        C1 = ApD - AnD;
        C2 = (ApD2 - AnD2) * 0.5f;
        C3 = (ApD3 - AnD3) * (1.0f / 6.0f);
    }
    const int c  = m / MCH;
    const int ml = m - c * MCH;
    const int s  = ml >> 3;
    const int q  = (ml >> 1) & 3;
    const int h  = (ml & 1) * 4;
    _Float16* dst = Cr + (((((size_t)c * NSTEP + s) * 4 + q) * 128 + n) * 8 + h);
    dst[0] = (_Float16)C0;
    dst[1] = (_Float16)C1;
    dst[2] = (_Float16)C2;
    dst[3] = (_Float16)C3;
}

// ---------------------------------------------------------------------------
// K3 main: MFMA micro-GEMM. 768 blocks (64 p-blocks x 12 chunks), 256 thr.
// F (A-operand) built in LDS in fragment order [sq][p] half8 via float4
// x-loads (rows 16B-aligned; chunk boundaries straddling m=784 fall back to
// the element path). B streamed from Cr (coalesced 16B). Epilogue:
// unsafeAtomicAdd into out (zeroed by K1; 12 adds/output, bit-stable R4-R8).
__global__ __launch_bounds__(256) void memristor_main(
        const float* __restrict__ x, const _Float16* __restrict__ Cr,
        float* __restrict__ out) {
    const int bid = blockIdx.x;
    const int ch  = bid % NCHK;
    const int pb  = bid / NCHK;
    const int p0  = pb * 16;
    const int m0  = ch * MCH;
    const int t   = threadIdx.x;

    __shared__ half8 F_lds[36 * 16];               // [sq][p], 9216 B
    const int NF4 = MCH / 4;                       // 18 float4 per row
    for (int idx = t; idx < 16 * NF4; idx += 256) {
        const int p     = idx / NF4;
        const int f4    = idx - p * NF4;
        const int mbase = m0 + f4 * 4;
        float xv[4];
        if (mbase + 3 < N_IN) {
            float4 v = *(const float4*)(x + (size_t)(p0 + p) * N_IN + mbase);
            xv[0] = v.x; xv[1] = v.y; xv[2] = v.z; xv[3] = v.w;
        } else {
            #pragma unroll
            for (int u = 0; u < 4; ++u) {
                int m = mbase + u;
                xv[u] = (m < N_IN) ? x[(size_t)(p0 + p) * N_IN + m] : -1.0f;
            }
        }
        #pragma unroll
        for (int u = 0; u < 4; ++u) {
            const int m  = mbase + u;
            const int ml = m - m0;
            float e;
            if (m < N_IN)
                e = (xv[u] > 0.0f) ? __builtin_amdgcn_logf(2.0f * xv[u]) : -1.0e4f;
            else
                e = (m == N_IN) ? 1.0f : -1.0e4f;  // bias row; pads -> F = 0
            float F0 = __builtin_amdgcn_exp2f(e * L_AVG_F);
            float F1 = F0 * e, F2 = F1 * e, F3 = F2 * e;
            _Float16* dst = (_Float16*)&F_lds[(ml >> 1) * 16 + p] + (ml & 1) * 4;
            dst[0] = (_Float16)F0;
            dst[1] = (_Float16)F1;
            dst[2] = (_Float16)F2;
            dst[3] = (_Float16)F3;
        }
    }
    __syncthreads();

    const int lane = t & 63;
    const int w    = t >> 6;
    const int quad = lane >> 4;
    const int col  = lane & 15;
    const int n0   = w * 32;                       // wave covers n0..n0+31 (2 tiles)

    const _Float16* __restrict__ Bb = Cr + (size_t)ch * (NSTEP * 4 * 128 * 8);

    f32x4 acc0 = {0.f, 0.f, 0.f, 0.f};
    f32x4 acc1 = {0.f, 0.f, 0.f, 0.f};
    #pragma unroll
    for (int s = 0; s < NSTEP; ++s) {
        half8 a  = F_lds[(s * 4 + quad) * 16 + col];                       // ds_read_b128
        half8 b0 = *(const half8*)(Bb + (((s * 4 + quad) * 128) + n0 + col) * 8);
        half8 b1 = *(const half8*)(Bb + (((s * 4 + quad) * 128) + n0 + 16 + col) * 8);
        acc0 = __builtin_amdgcn_mfma_f32_16x16x32_f16(a, b0, acc0, 0, 0, 0);
        acc1 = __builtin_amdgcn_mfma_f32_16x16x32_f16(a, b1, acc1, 0, 0, 0);
    }

    // D layout: row = quad*4 + r, col = lane&15. 8 coalesced f32 atomics/lane.
    float* obase = out + (size_t)(p0 + quad * 4) * N_OUT;
    #pragma unroll
    for (int r = 0; r < 4; ++r) {
        unsafeAtomicAdd(&obase[(size_t)r * N_OUT + n0 + col],      acc0[r]);
        unsafeAtomicAdd(&obase[(size_t)r * N_OUT + n0 + 16 + col], acc1[r]);
    }
}

// ---------------------------------------------------------------------------
extern "C" void kernel_launch(void* const* d_in, const int* in_sizes, int n_in,
                              void* d_out, int out_size, void* d_ws, size_t ws_size,
                              hipStream_t stream) {
    const float* x  = (const float*)d_in[0];
    const float* wp = (const float*)d_in[1];
    const float* wn = (const float*)d_in[2];
    const float* bp = (const float*)d_in[3];
    const float* bn = (const float*)d_in[4];
    const float* np = (const float*)d_in[5];
    float* out = (float*)d_out;

    float*     partial = (float*)((char*)d_ws + PART_MAX_OFF);
    _Float16*  Cr      = (_Float16*)((char*)d_ws + CR_OFF);

    max_reduce_zero<<<NB_MAX, 256, 0, stream>>>(wp, wn, bp, bn, partial, (float4*)out);
    precompute_c<<<(M_TOT * 128) / 256, 256, 0, stream>>>(wp, wn, bp, bn, np, partial, Cr);
    memristor_main<<<NB_MAIN, 256, 0, stream>>>(x, Cr, out);
}